// Round 5
// baseline (217.452 us; speedup 1.0000x reference)
//
#include <hip/hip_runtime.h>
#include <hip/hip_bf16.h>

typedef unsigned short u16;
typedef unsigned int u32;
typedef __attribute__((ext_vector_type(8))) short bf16x8;
typedef __attribute__((ext_vector_type(4))) float f32x4;
typedef __attribute__((ext_vector_type(4))) u16 u16x4;
typedef __attribute__((ext_vector_type(8))) u16 u16x8;

#define B_ 64
#define R_ 2
#define T_ 32
#define N_ 128
#define C_ 64

__device__ __forceinline__ u16 f2bf(float f) {
  return __builtin_bit_cast(u16, __float2bfloat16(f));
}
__device__ __forceinline__ float bf2f(u16 h) {
  u32 u = ((u32)h) << 16;
  return __builtin_bit_cast(float, u);
}

#define MFMA __builtin_amdgcn_mfma_f32_16x16x32_bf16

// barrier that does NOT drain vmcnt: in-flight global loads/stores survive.
#define BAR()                                                  \
  do {                                                         \
    asm volatile("s_waitcnt lgkmcnt(0)" ::: "memory");         \
    __builtin_amdgcn_s_barrier();                              \
    __builtin_amdgcn_sched_barrier(0);                         \
  } while (0)

// ---- row-owner A-chunk staging: chunk = 64 rows x 128 f32 (32 KB).
// thread (arow=tid>>2, aseg=tid&3) owns 32 contiguous floats of row arow.
__device__ __forceinline__ void a_load(float4* av, const float* Aslice, int ch, int tid) {
  const int arow = tid >> 2, aseg = tid & 3;
  const float* ap = Aslice + (size_t)(ch * 64 + arow) * N_ + aseg * 32;
#pragma unroll
  for (int j = 0; j < 8; ++j) av[j] = *(const float4*)(ap + 4 * j);
}
__device__ __forceinline__ void a_store(const float4* av, float* Oslice, int ch, int tid) {
  const int arow = tid >> 2, aseg = tid & 3;
  float* op = Oslice + (size_t)(ch * 64 + arow) * N_ + aseg * 32;
#pragma unroll
  for (int j = 0; j < 8; ++j) *(float4*)(op + 4 * j) = av[j];
}

// rowsum -> dinv_r[n]; transpose-write AT[m][arow ^ (aseg<<4)] with +I and
// dinv[n] folded. Write pattern ~2-way bank (measured-fine R1/R2).
__device__ __forceinline__ void at_write(const float4* av, int ch, int tid,
                                         u16 (*AT)[72], float* dinvr) {
  const int arow = tid >> 2, aseg = tid & 3;
  const int n = ch * 64 + arow;
  float part = 0.f;
#pragma unroll
  for (int j = 0; j < 8; ++j) part += (av[j].x + av[j].y) + (av[j].z + av[j].w);
  part += __shfl_xor(part, 1);
  part += __shfl_xor(part, 2);
  const float d = rsqrtf(part + 1.0f);
  if (aseg == 0) dinvr[n] = d;
  const int col = arow ^ (aseg << 4);
#pragma unroll
  for (int j = 0; j < 8; ++j) {
#pragma unroll
    for (int k = 0; k < 4; ++k) {
      const int m = aseg * 32 + 4 * j + k;
      float v = ((const float*)&av[j])[k];
      if (m == n) v += 1.0f;
      AT[m][col] = f2bf(v * d);
    }
  }
}

__device__ __forceinline__ void load_wg(bf16x8 wf[2][2], const float* wg, int r,
                                        int wr, int lr, int lg) {
#pragma unroll
  for (int kk = 0; kk < 2; ++kk)
#pragma unroll
    for (int mr = 0; mr < 2; ++mr) {
      const float* p = wg + ((size_t)(r * C_ + 32 * wr + 16 * mr + lr)) * C_ + 32 * kk + 8 * lg;
      float4 a = *(const float4*)p, b = *(const float4*)(p + 4);
      bf16x8 f;
      f[0] = (short)f2bf(a.x); f[1] = (short)f2bf(a.y);
      f[2] = (short)f2bf(a.z); f[3] = (short)f2bf(a.w);
      f[4] = (short)f2bf(b.x); f[5] = (short)f2bf(b.y);
      f[6] = (short)f2bf(b.z); f[7] = (short)f2bf(b.w);
      wf[kk][mr] = f;
    }
}

// mm1: TMP[o][n ^ ((o&3)<<4)] = sum_c W[o][c]*X[c][n] + bias[o]
__device__ __forceinline__ void mm1f(u16 (*TMP)[128], const bf16x8 wf[2][2],
                                     const bf16x8 bfr[2][4], const float4 bias[2],
                                     int wr, int wc, int lr, int lg) {
  f32x4 acc1[2][4] = {};
#pragma unroll
  for (int kk = 0; kk < 2; ++kk)
#pragma unroll
    for (int mr = 0; mr < 2; ++mr)
#pragma unroll
      for (int nc = 0; nc < 4; ++nc)
        acc1[mr][nc] = MFMA(wf[kk][mr], bfr[kk][nc], acc1[mr][nc], 0, 0, 0);
#pragma unroll
  for (int mr = 0; mr < 2; ++mr) {
    const int o0 = 32 * wr + 16 * mr + 4 * lg;
    const float bb[4] = {bias[mr].x, bias[mr].y, bias[mr].z, bias[mr].w};
#pragma unroll
    for (int nc = 0; nc < 4; ++nc) {
      const int n = 64 * wc + 16 * nc + lr;
#pragma unroll
      for (int i = 0; i < 4; ++i)
        TMP[o0 + i][n ^ (i << 4)] = f2bf(acc1[mr][nc][i] + bb[i]);
    }
  }
}

// mm2 over one 64-wide n-chunk (2 K=32 steps), b128 LDS reads
__device__ __forceinline__ void mm2_half(f32x4 accr[2][4], const u16 (*TMP)[128],
                                         const u16 (*AT)[72], int ch,
                                         int wr, int wc, int lr, int lg) {
#pragma unroll
  for (int kkin = 0; kkin < 2; ++kkin) {
    bf16x8 af[2], bfr[4];
#pragma unroll
    for (int mr = 0; mr < 2; ++mr) {
      const int c = 32 * wr + 16 * mr + lr;
      const int colT = (ch * 64 + 32 * kkin + 8 * lg) ^ ((lr & 3) << 4);
      af[mr] = *(const bf16x8*)&TMP[c][colT];
    }
#pragma unroll
    for (int nc = 0; nc < 4; ++nc) {
      const int m = 64 * wc + 16 * nc + lr;
      const int colA = (32 * kkin + 8 * lg) ^ (((m >> 5) & 3) << 4);
      bfr[nc] = *(const bf16x8*)&AT[m][colA];
    }
#pragma unroll
    for (int mr = 0; mr < 2; ++mr)
#pragma unroll
      for (int nc = 0; nc < 4; ++nc)
        accr[mr][nc] = MFMA(af[mr], bfr[nc], accr[mr][nc], 0, 0, 0);
  }
}

__device__ __forceinline__ void fold(f32x4 acc2[2][4], f32x4 accr[2][4],
                                     const float* dinvr, int wc, int lr) {
#pragma unroll
  for (int nc = 0; nc < 4; ++nc) {
    const float dm = dinvr[64 * wc + 16 * nc + lr];
#pragma unroll
    for (int mr = 0; mr < 2; ++mr)
#pragma unroll
      for (int i = 0; i < 4; ++i) {
        acc2[mr][nc][i] += dm * accr[mr][nc][i];
        accr[mr][nc][i] = 0.f;
      }
  }
}

// ---------------------------------------------------------------------------
// K1: per (b,t). 4 chunks (r x half): register-staged A, double-buffered bf16
// AT tiles, raw barriers (loads/stores stay in flight).
// LDS = 2*18432 + 16384 + 1024 = 54272 B.
// ---------------------------------------------------------------------------
__global__ __launch_bounds__(256, 2) void k_gcn(
    const float* __restrict__ x, const float* __restrict__ A,
    const float* __restrict__ wg, const float* __restrict__ bg,
    float* __restrict__ outA, u16* __restrict__ wsX) {
  __shared__ __align__(16) u16 AT[2][N_][72];
  __shared__ __align__(16) u16 TMP[C_][128];  // aliases X^T stage + epilogue stage
  __shared__ float dinv[R_][N_];

  const int tid = threadIdx.x;
  const int bid = ((blockIdx.x & 7) << 8) | (blockIdx.x >> 3);  // XCD swizzle
  const int b = bid >> 5, t = bid & 31;
  const int lane = tid & 63, wv = tid >> 6;
  const int wr = wv >> 1, wc = wv & 1;
  const int lr = lane & 15, lg = lane >> 4;

  const size_t Asl0 = ((size_t)((b * R_ + 0) * T_ + t)) * (size_t)(N_ * N_);
  const size_t Asl1 = ((size_t)((b * R_ + 1) * T_ + t)) * (size_t)(N_ * N_);

  // ---- prologue: issue everything
  float4 xv[8];
  {
    const int c = tid & 63, ub = tid >> 6;
    const float* xp = x + ((size_t)(b * C_ + c) * T_ + t) * N_ + 32 * ub;
#pragma unroll
    for (int j = 0; j < 8; ++j) xv[j] = *(const float4*)(xp + 4 * j);
  }
  float4 avA[8], avB[8];
  a_load(avA, A + Asl0, 0, tid);
  a_load(avB, A + Asl0, 1, tid);
  bf16x8 wf0[2][2], wf1[2][2];
  load_wg(wf0, wg, 0, wr, lr, lg);
  load_wg(wf1, wg, 1, wr, lr, lg);
  float4 bias[R_][2];
#pragma unroll
  for (int r = 0; r < R_; ++r)
#pragma unroll
    for (int mr = 0; mr < 2; ++mr)
      bias[r][mr] = *(const float4*)(bg + r * C_ + 32 * wr + 16 * mr + 4 * lg);

  // X^T bf16 (swizzled) into TMP space
  u16 (*XT)[64] = (u16(*)[64])TMP;
  {
    const int c = tid & 63, ub = tid >> 6;
#pragma unroll
    for (int j = 0; j < 8; ++j) {
      const int n0 = 32 * ub + 4 * j;
      XT[n0 + 0][c] = f2bf(xv[j].x);
      XT[n0 + 1][c ^ 16] = f2bf(xv[j].y);
      XT[n0 + 2][c ^ 32] = f2bf(xv[j].z);
      XT[n0 + 3][c ^ 48] = f2bf(xv[j].w);
    }
  }
  BAR();

  // mm1 B-fragments (r-independent) to registers
  bf16x8 bfrx[2][4];
#pragma unroll
  for (int kk = 0; kk < 2; ++kk)
#pragma unroll
    for (int nc = 0; nc < 4; ++nc) {
      const int n = 64 * wc + 16 * nc + lr;
      const int col = (32 * kk + 8 * lg) ^ ((lr & 3) << 4);
      bfrx[kk][nc] = *(const bf16x8*)&XT[n][col];
    }
  BAR();  // XT fully read; TMP reusable

  // P-1: mm1 r0 -> TMP; consume chunk0; (chunk1 still in flight)
  mm1f(TMP, wf0, bfrx, bias[0], wr, wc, lr, lg);
  at_write(avA, 0, tid, AT[0], dinv[0]);
  a_store(avA, outA + Asl0, 0, tid);
  BAR();

  f32x4 acc2[2][4] = {};
  f32x4 accr[2][4] = {};

  // P0: load r1-ch0 | mm2(ch0) | consume chunk1
  a_load(avA, A + Asl1, 0, tid);
  mm2_half(accr, TMP, AT[0], 0, wr, wc, lr, lg);
  at_write(avB, 1, tid, AT[1], dinv[0]);
  a_store(avB, outA + Asl0, 1, tid);
  BAR();

  // P1: load r1-ch1 | mm2(ch1) + fold r0 | consume r1-ch0
  a_load(avB, A + Asl1, 1, tid);
  mm2_half(accr, TMP, AT[1], 1, wr, wc, lr, lg);
  fold(acc2, accr, dinv[0], wc, lr);
  at_write(avA, 0, tid, AT[0], dinv[1]);
  a_store(avA, outA + Asl1, 0, tid);
  BAR();

  // P2a: mm1 r1 -> TMP
  mm1f(TMP, wf1, bfrx, bias[1], wr, wc, lr, lg);
  BAR();

  // P2b: mm2(r1-ch0) | consume r1-ch1
  mm2_half(accr, TMP, AT[0], 0, wr, wc, lr, lg);
  at_write(avB, 1, tid, AT[1], dinv[1]);
  a_store(avB, outA + Asl1, 1, tid);
  BAR();

  // P3: mm2(r1-ch1) + fold r1
  mm2_half(accr, TMP, AT[1], 1, wr, wc, lr, lg);
  fold(acc2, accr, dinv[1], wc, lr);
  BAR();  // TMP readers done -> reusable as epilogue stage

  // epilogue: stage (swizzled) -> coalesced u16x8 stores
  u16* stage = &TMP[0][0];
#pragma unroll
  for (int mr = 0; mr < 2; ++mr)
#pragma unroll
    for (int nc = 0; nc < 4; ++nc) {
      const int m = 64 * wc + 16 * nc + lr;
      const int c0 = 32 * wr + 16 * mr + 4 * lg;
#pragma unroll
      for (int i = 0; i < 4; ++i)
        stage[m * 64 + ((c0 + i) ^ ((m & 7) << 3))] = f2bf(acc2[mr][nc][i]);
    }
  BAR();
  {
    u16* wp = wsX + ((size_t)(b * T_ + t) * N_) * C_;
#pragma unroll
    for (int it = 0; it < 4; ++it) {
      const int idx = it * 2048 + tid * 8;
      const int m = idx >> 6, a = idx & 63;
      u16x8 v = *(const u16x8*)&stage[m * 64 + a];
      *(u16x8*)(wp + m * 64 + (a ^ ((m & 7) << 3))) = v;
    }
  }
}

// ---------------------------------------------------------------------------
// K2: per (b,t): h = prelu(x_comb); out = prelu(conv3_T(h) + b_tcn + x)
// ---------------------------------------------------------------------------
__global__ __launch_bounds__(256, 3) void k_tcn(
    const u16* __restrict__ wsX, const float* __restrict__ x,
    const float* __restrict__ wt, const float* __restrict__ bt,
    const float* __restrict__ a_tcn, const float* __restrict__ a_out,
    float* __restrict__ out) {
  __shared__ __align__(16) u16 HT[N_][200];
  const int tid = threadIdx.x;
  const int bid = ((blockIdx.x & 7) << 8) | (blockIdx.x >> 3);  // XCD swizzle
  const int b = bid >> 5, t = bid & 31;
  const int lane = tid & 63, wv = tid >> 6;
  const int wr = wv >> 1, wc = wv & 1;
  const int lr = lane & 15, lg = lane >> 4;
  const float at = a_tcn[0], ao = a_out[0];

  bf16x8 wfr[6][2];
#pragma unroll
  for (int kk = 0; kk < 6; ++kk) {
    const int dt = kk >> 1;
    const int ci0 = (32 * kk + 8 * lg) & 63;
#pragma unroll
    for (int mr = 0; mr < 2; ++mr) {
      const int co = 32 * wr + 16 * mr + lr;
      const float* p = wt + ((size_t)co * C_ + ci0) * 3 + dt;
      float e[8];
#pragma unroll
      for (int j = 0; j < 8; ++j) e[j] = p[3 * j];
      bf16x8 f;
#pragma unroll
      for (int j = 0; j < 8; ++j) f[j] = (short)f2bf(e[j]);
      wfr[kk][mr] = f;
    }
  }

#pragma unroll
  for (int dt = 0; dt < 3; ++dt) {
    const int t2 = t + dt - 1;
    const bool ok = (t2 >= 0) && (t2 < T_);
    const u16* p = wsX + ((size_t)(b * T_ + (ok ? t2 : 0)) * N_) * C_;
    u16x4 hv[8];
#pragma unroll
    for (int it = 0; it < 8; ++it) {
      const int idx = it * 256 + tid;
      const int n = idx >> 4, c4 = (idx & 15) * 4;
      u16x4 z = {0, 0, 0, 0};
      hv[it] = ok ? *(const u16x4*)(p + n * C_ + c4) : z;
    }
#pragma unroll
    for (int it = 0; it < 8; ++it) {
      const int idx = it * 256 + tid;
      const int n = idx >> 4, c4 = (idx & 15) * 4;
      u16x4 o;
#pragma unroll
      for (int j = 0; j < 4; ++j) {
        float f = bf2f(hv[it][j]);
        o[j] = f2bf(f < 0.f ? at * f : f);
      }
      *(u16x4*)&HT[n][dt * 64 + c4] = o;
    }
  }
  __syncthreads();

  f32x4 acc[2][4] = {};
#pragma unroll
  for (int kk = 0; kk < 6; ++kk) {
    bf16x8 bfr[4];
#pragma unroll
    for (int nc = 0; nc < 4; ++nc)
      bfr[nc] = *(const bf16x8*)&HT[64 * wc + 16 * nc + lr][32 * kk + 8 * lg];
#pragma unroll
    for (int mr = 0; mr < 2; ++mr)
#pragma unroll
      for (int nc = 0; nc < 4; ++nc)
        acc[mr][nc] = MFMA(wfr[kk][mr], bfr[nc], acc[mr][nc], 0, 0, 0);
  }

#pragma unroll
  for (int mr = 0; mr < 2; ++mr) {
    const int co0 = 32 * wr + 16 * mr + 4 * lg;
    float bts[4];
#pragma unroll
    for (int i = 0; i < 4; ++i) bts[i] = bt[co0 + i];
#pragma unroll
    for (int nc = 0; nc < 4; ++nc) {
      const int n = 64 * wc + 16 * nc + lr;
#pragma unroll
      for (int i = 0; i < 4; ++i) {
        const size_t gi = ((size_t)(b * C_ + co0 + i) * T_ + t) * N_ + n;
        float v = acc[mr][nc][i] + bts[i] + x[gi];
        out[gi] = (v < 0.f) ? ao * v : v;
      }
    }
  }
}

extern "C" void kernel_launch(void* const* d_in, const int* in_sizes, int n_in,
                              void* d_out, int out_size, void* d_ws, size_t ws_size,
                              hipStream_t stream) {
  const float* x = (const float*)d_in[0];
  const float* A = (const float*)d_in[1];
  const float* wg = (const float*)d_in[2];
  const float* bg = (const float*)d_in[3];
  const float* wt = (const float*)d_in[4];
  const float* bt = (const float*)d_in[5];
  const float* atc = (const float*)d_in[6];
  const float* aoc = (const float*)d_in[7];
  float* out = (float*)d_out;
  float* outA = out + (size_t)B_ * C_ * T_ * N_;  // second tuple element: A copy
  u16* wsX = (u16*)d_ws;                          // bf16 x_comb, (B,T,N,C)

  k_gcn<<<B_ * T_, 256, 0, stream>>>(x, A, wg, bg, outA, wsX);
  k_tcn<<<B_ * T_, 256, 0, stream>>>(wsX, x, wt, bt, atc, aoc, out);
}